// Round 1
// baseline (240.969 us; speedup 1.0000x reference)
//
#include <hip/hip_runtime.h>

#define NROWS 4096
#define DDIM  256
#define MARGIN 0.1f

// ---------------- Kernel A: diag[i] = <v_i, t_i> ----------------
// One wave per row; lane l loads float4 at offset 4l (64*4 = 256 = D).
__global__ __launch_bounds__(256) void diag_kernel(
    const float* __restrict__ v, const float* __restrict__ t,
    float* __restrict__ diag) {
  const int wave = threadIdx.x >> 6;
  const int lane = threadIdx.x & 63;
  const int row  = blockIdx.x * 4 + wave;
  const float4 a = ((const float4*)(v + (size_t)row * DDIM))[lane];
  const float4 b = ((const float4*)(t + (size_t)row * DDIM))[lane];
  float s = a.x*b.x + a.y*b.y + a.z*b.z + a.w*b.w;
  #pragma unroll
  for (int off = 32; off; off >>= 1) s += __shfl_down(s, off);
  if (lane == 0) diag[row] = s;
}

// ---------------- Kernel B: fused GEMM tile + epilogue ----------------
// 128x128 tile per block, 256 threads, 8x8 register tile per thread.
// LDS tiles stored k-major (transposed) so fragments are contiguous float4s.
__global__ __launch_bounds__(256) void main_kernel(
    const float* __restrict__ v, const float* __restrict__ t,
    const float* __restrict__ diag, float* __restrict__ sums,
    int* __restrict__ rank) {
  __shared__ float sv[16][132];   // [k][i], +4 pad keeps 16B align, breaks pow2 stride
  __shared__ float st[16][132];   // [k][j]

  const int tid = threadIdx.x;
  const int i0  = blockIdx.y * 128;
  const int j0  = blockIdx.x * 128;
  const int tr  = tid >> 4;       // 0..15 -> rows i0 + tr*8 .. +7
  const int tc  = tid & 15;       // 0..15 -> cols j0 + tc*8 .. +7

  float acc[8][8];
  #pragma unroll
  for (int r = 0; r < 8; ++r)
    #pragma unroll
    for (int c = 0; c < 8; ++c) acc[r][c] = 0.f;

  const int srow = tid >> 1;        // 0..127 staged row
  const int sk   = (tid & 1) * 8;   // k sub-offset 0 or 8

  for (int k0 = 0; k0 < DDIM; k0 += 16) {
    const float4 av0 = *(const float4*)(v + (size_t)(i0 + srow) * DDIM + k0 + sk);
    const float4 av1 = *(const float4*)(v + (size_t)(i0 + srow) * DDIM + k0 + sk + 4);
    const float4 at0 = *(const float4*)(t + (size_t)(j0 + srow) * DDIM + k0 + sk);
    const float4 at1 = *(const float4*)(t + (size_t)(j0 + srow) * DDIM + k0 + sk + 4);
    __syncthreads();   // protect previous iteration's reads
    sv[sk+0][srow] = av0.x; sv[sk+1][srow] = av0.y; sv[sk+2][srow] = av0.z; sv[sk+3][srow] = av0.w;
    sv[sk+4][srow] = av1.x; sv[sk+5][srow] = av1.y; sv[sk+6][srow] = av1.z; sv[sk+7][srow] = av1.w;
    st[sk+0][srow] = at0.x; st[sk+1][srow] = at0.y; st[sk+2][srow] = at0.z; st[sk+3][srow] = at0.w;
    st[sk+4][srow] = at1.x; st[sk+5][srow] = at1.y; st[sk+6][srow] = at1.z; st[sk+7][srow] = at1.w;
    __syncthreads();

    #pragma unroll
    for (int kk = 0; kk < 16; ++kk) {
      const float4 a0 = *(const float4*)&sv[kk][tr*8];
      const float4 a1 = *(const float4*)&sv[kk][tr*8+4];
      const float4 b0 = *(const float4*)&st[kk][tc*8];
      const float4 b1 = *(const float4*)&st[kk][tc*8+4];
      const float a[8] = {a0.x,a0.y,a0.z,a0.w,a1.x,a1.y,a1.z,a1.w};
      const float b[8] = {b0.x,b0.y,b0.z,b0.w,b1.x,b1.y,b1.z,b1.w};
      #pragma unroll
      for (int r = 0; r < 8; ++r)
        #pragma unroll
        for (int c = 0; c < 8; ++c)
          acc[r][c] = fmaf(a[r], b[c], acc[r][c]);
    }
  }

  // ---- fused epilogue: hinge sums + rank counts (exclude j==i by INDEX) ----
  float di[8], dj[8];
  #pragma unroll
  for (int r = 0; r < 8; ++r) di[r] = diag[i0 + tr*8 + r];
  #pragma unroll
  for (int c = 0; c < 8; ++c) dj[c] = diag[j0 + tc*8 + c];

  float vt = 0.f, tv = 0.f;
  int cnt[8];
  #pragma unroll
  for (int r = 0; r < 8; ++r) cnt[r] = 0;

  #pragma unroll
  for (int r = 0; r < 8; ++r) {
    const int gi = i0 + tr*8 + r;
    #pragma unroll
    for (int c = 0; c < 8; ++c) {
      const int gj = j0 + tc*8 + c;
      const float s = acc[r][c];
      if (gi != gj) {
        vt += fmaxf(0.f, MARGIN - di[r] + s);
        tv += fmaxf(0.f, MARGIN - dj[c] + s);
        cnt[r] += (s > di[r]) ? 1 : 0;
      }
    }
  }

  // counts: reduce across the 16 lanes sharing the same rows (same tr)
  #pragma unroll
  for (int r = 0; r < 8; ++r) {
    int c = cnt[r];
    c += __shfl_down(c, 8, 16);
    c += __shfl_down(c, 4, 16);
    c += __shfl_down(c, 2, 16);
    c += __shfl_down(c, 1, 16);
    if (tc == 0) atomicAdd(&rank[i0 + tr*8 + r], c);
  }

  // hinge sums: full-wave reduce, one atomic per wave per scalar
  #pragma unroll
  for (int off = 32; off; off >>= 1) {
    vt += __shfl_down(vt, off);
    tv += __shfl_down(tv, off);
  }
  if ((tid & 63) == 0) {
    atomicAdd(&sums[0], vt);
    atomicAdd(&sums[1], tv);
  }
}

// ---------------- Kernel C: final reduction -> 6 outputs ----------------
__global__ __launch_bounds__(256) void final_kernel(
    const float* __restrict__ sums, const int* __restrict__ rank,
    float* __restrict__ out) {
  __shared__ int s1[4], s5[4], s10[4], ssum[4];
  const int tid = threadIdx.x;
  int c1 = 0, c5 = 0, c10 = 0, cs = 0;
  for (int i = tid; i < NROWS; i += 256) {
    const int r = rank[i];
    c1  += (r < 1);
    c5  += (r < 5);
    c10 += (r < 10);
    cs  += r;
  }
  #pragma unroll
  for (int off = 32; off; off >>= 1) {
    c1  += __shfl_down(c1, off);
    c5  += __shfl_down(c5, off);
    c10 += __shfl_down(c10, off);
    cs  += __shfl_down(cs, off);
  }
  const int w = tid >> 6;
  if ((tid & 63) == 0) { s1[w] = c1; s5[w] = c5; s10[w] = c10; ssum[w] = cs; }
  __syncthreads();
  if (tid == 0) {
    int a1 = 0, a5 = 0, a10 = 0, as = 0;
    for (int k = 0; k < 4; ++k) { a1 += s1[k]; a5 += s5[k]; a10 += s10[k]; as += ssum[k]; }
    const float denom = 4096.0f * 4095.0f;
    out[0] = sums[0] / denom;          // vt_loss
    out[1] = sums[1] / denom;          // tv_loss
    out[2] = a1  / 4096.0f;            // recall@1
    out[3] = a5  / 4096.0f;            // recall@5
    out[4] = a10 / 4096.0f;            // recall@10
    out[5] = (float)as / 4096.0f;      // mean rank
  }
}

extern "C" void kernel_launch(void* const* d_in, const int* in_sizes, int n_in,
                              void* d_out, int out_size, void* d_ws, size_t ws_size,
                              hipStream_t stream) {
  const float* v = (const float*)d_in[0];
  const float* t = (const float*)d_in[1];
  float* out = (float*)d_out;

  // ws layout: [0,16K) diag (4096 f32) | [16K,32K) rank (4096 i32) | [32K,+8) sums
  float* diag = (float*)d_ws;
  int*   rank = (int*)((char*)d_ws + NROWS * sizeof(float));
  float* sums = (float*)((char*)d_ws + 2 * (size_t)NROWS * sizeof(float));

  // ws is re-poisoned to 0xAA before every call: zero the accumulators.
  hipMemsetAsync((char*)d_ws + NROWS * sizeof(float), 0,
                 NROWS * sizeof(int) + 2 * sizeof(float), stream);

  hipLaunchKernelGGL(diag_kernel, dim3(NROWS / 4), dim3(256), 0, stream, v, t, diag);
  hipLaunchKernelGGL(main_kernel, dim3(32, 32), dim3(256), 0, stream,
                     v, t, diag, sums, rank);
  hipLaunchKernelGGL(final_kernel, dim3(1), dim3(256), 0, stream, sums, rank, out);
}

// Round 2
// 147.826 us; speedup vs baseline: 1.6301x; 1.6301x over previous
//
#include <hip/hip_runtime.h>

#define NROWS 4096
#define DDIM  256
#define MARGIN 0.1f

typedef __attribute__((ext_vector_type(4)))  _Float16 half4;
typedef __attribute__((ext_vector_type(8)))  _Float16 half8;
typedef __attribute__((ext_vector_type(16))) float    floatx16;

// ---------------- Kernel A: diag + zero accumulators ----------------
__global__ __launch_bounds__(256) void diag_kernel(
    const float* __restrict__ v, const float* __restrict__ t,
    float* __restrict__ diag, int* __restrict__ rank, float* __restrict__ sums) {
  const int wv   = threadIdx.x >> 6;
  const int lane = threadIdx.x & 63;
  const int row  = blockIdx.x * 4 + wv;
  const float4 a = ((const float4*)(v + (size_t)row * DDIM))[lane];
  const float4 b = ((const float4*)(t + (size_t)row * DDIM))[lane];
  float s = a.x*b.x + a.y*b.y + a.z*b.z + a.w*b.w;
  #pragma unroll
  for (int off = 32; off; off >>= 1) s += __shfl_down(s, off);
  if (lane == 0) { diag[row] = s; rank[row] = 0; }
  if (blockIdx.x == 0 && threadIdx.x < 2) sums[threadIdx.x] = 0.f;
}

// fp32 -> (hi, lo) fp16 split, RNE both. x = hi + lo to ~2^-22 rel.
__device__ inline void stage4(_Float16* __restrict__ dhi, _Float16* __restrict__ dlo,
                              const float4 x) {
  half4 h, l;
  h.x = (_Float16)x.x; l.x = (_Float16)(x.x - (float)h.x);
  h.y = (_Float16)x.y; l.y = (_Float16)(x.y - (float)h.y);
  h.z = (_Float16)x.z; l.z = (_Float16)(x.z - (float)h.z);
  h.w = (_Float16)x.w; l.w = (_Float16)(x.w - (float)h.w);
  *(half4*)dhi = h;
  *(half4*)dlo = l;
}

// ---------------- Kernel B: fused MFMA GEMM + epilogue ----------------
// Block tile 256(i) x 128(j), 4 waves of 128x64, 32x32x16 f16 MFMA,
// 3-term hi/lo split (hi*hi + hi*lo + lo*hi), K-slab 32 (2 K-steps).
// LDS row stride 40 halves (20 dwords, odd*4) -> conflict-free b128 frag reads.
__global__ __launch_bounds__(256, 2) void main_kernel(
    const float* __restrict__ v, const float* __restrict__ t,
    const float* __restrict__ diag, float* __restrict__ sums,
    int* __restrict__ rank) {
  __shared__ __align__(16) _Float16 Ahi[256 * 40];
  __shared__ __align__(16) _Float16 Alo[256 * 40];
  __shared__ __align__(16) _Float16 Bhi[128 * 40];
  __shared__ __align__(16) _Float16 Blo[128 * 40];
  __shared__ float sdi[256];
  __shared__ float sdj[128];

  const int tid  = threadIdx.x;
  const int w    = tid >> 6;
  const int lane = tid & 63;
  const int i0   = blockIdx.y * 256;
  const int j0   = blockIdx.x * 128;

  sdi[tid] = diag[i0 + tid];
  if (tid < 128) sdj[tid] = diag[j0 + tid];

  floatx16 acc[4][2];
  #pragma unroll
  for (int mt = 0; mt < 4; ++mt)
    #pragma unroll
    for (int nt = 0; nt < 2; ++nt)
      #pragma unroll
      for (int r = 0; r < 16; ++r) acc[mt][nt][r] = 0.f;

  // staging map: 8 lanes span one row's 32-float K-slab (128B contiguous/8 lanes)
  const int srow = tid >> 3;         // 0..31
  const int skc  = (tid & 7) * 4;    // 0,4,...,28
  const float* vp = v + (size_t)(i0 + srow) * DDIM + skc;
  const float* tp = t + (size_t)(j0 + srow) * DDIM + skc;

  float4 pa[8], pb[4];
  #pragma unroll
  for (int p = 0; p < 8; ++p) pa[p] = *(const float4*)(vp + (size_t)p * 32 * DDIM);
  #pragma unroll
  for (int p = 0; p < 4; ++p) pb[p] = *(const float4*)(tp + (size_t)p * 32 * DDIM);

  // fragment base offsets (in halves)
  const int mrow  = lane & 31;
  const int khalf = (lane >> 5) * 8;
  const int abase = ((w >> 1) * 128 + mrow) * 40 + khalf;
  const int bbase = ((w & 1) * 64 + mrow) * 40 + khalf;

  for (int s = 0; s < 8; ++s) {
    __syncthreads();   // previous compute done reading LDS
    #pragma unroll
    for (int p = 0; p < 8; ++p)
      stage4(&Ahi[(srow + p * 32) * 40 + skc], &Alo[(srow + p * 32) * 40 + skc], pa[p]);
    #pragma unroll
    for (int p = 0; p < 4; ++p)
      stage4(&Bhi[(srow + p * 32) * 40 + skc], &Blo[(srow + p * 32) * 40 + skc], pb[p]);
    __syncthreads();

    if (s < 7) {   // prefetch next slab; overlaps with MFMA below
      #pragma unroll
      for (int p = 0; p < 8; ++p)
        pa[p] = *(const float4*)(vp + (size_t)p * 32 * DDIM + (s + 1) * 32);
      #pragma unroll
      for (int p = 0; p < 4; ++p)
        pb[p] = *(const float4*)(tp + (size_t)p * 32 * DDIM + (s + 1) * 32);
    }

    #pragma unroll
    for (int ks = 0; ks < 2; ++ks) {
      half8 bh[2], bl[2];
      #pragma unroll
      for (int nt = 0; nt < 2; ++nt) {
        bh[nt] = *(const half8*)&Bhi[bbase + nt * 32 * 40 + ks * 16];
        bl[nt] = *(const half8*)&Blo[bbase + nt * 32 * 40 + ks * 16];
      }
      #pragma unroll
      for (int mt = 0; mt < 4; ++mt) {
        const half8 ah = *(const half8*)&Ahi[abase + mt * 32 * 40 + ks * 16];
        const half8 al = *(const half8*)&Alo[abase + mt * 32 * 40 + ks * 16];
        #pragma unroll
        for (int nt = 0; nt < 2; ++nt) {
          acc[mt][nt] = __builtin_amdgcn_mfma_f32_32x32x16_f16(al, bh[nt], acc[mt][nt], 0, 0, 0);
          acc[mt][nt] = __builtin_amdgcn_mfma_f32_32x32x16_f16(ah, bl[nt], acc[mt][nt], 0, 0, 0);
          acc[mt][nt] = __builtin_amdgcn_mfma_f32_32x32x16_f16(ah, bh[nt], acc[mt][nt], 0, 0, 0);
        }
      }
    }
  }

  // ---- epilogue: C/D layout col=lane&31, row=(reg&3)+8*(reg>>2)+4*(lane>>5) ----
  float vt = 0.f, tv = 0.f;
  const int h    = lane >> 5;
  const int colL = lane & 31;
  #pragma unroll
  for (int mt = 0; mt < 4; ++mt) {
    const int rbase = (w >> 1) * 128 + mt * 32;
    #pragma unroll
    for (int reg = 0; reg < 16; ++reg) {
      const int r  = (reg & 3) + 8 * (reg >> 2) + 4 * h;
      const int gi = i0 + rbase + r;
      const float di = sdi[rbase + r];
      unsigned long long b0 = 0, b1 = 0;
      #pragma unroll
      for (int nt = 0; nt < 2; ++nt) {
        const int c  = (w & 1) * 64 + nt * 32 + colL;
        const int gj = j0 + c;
        const float s  = acc[mt][nt][reg];
        const float dj = sdj[c];
        const bool ne = (gi != gj);
        if (ne) {
          vt += fmaxf(0.f, MARGIN - di + s);
          tv += fmaxf(0.f, MARGIN - dj + s);
        }
        const unsigned long long bb = __ballot(ne && (s > di));
        if (nt == 0) b0 = bb; else b1 = bb;
      }
      if (colL == 0) {
        const int c = h ? (int)(__popcll(b0 >> 32) + __popcll(b1 >> 32))
                        : (int)(__popcll(b0 & 0xFFFFFFFFull) + __popcll(b1 & 0xFFFFFFFFull));
        atomicAdd(&rank[gi], c);
      }
    }
  }
  #pragma unroll
  for (int off = 32; off; off >>= 1) {
    vt += __shfl_down(vt, off);
    tv += __shfl_down(tv, off);
  }
  if (lane == 0) {
    atomicAdd(&sums[0], vt);
    atomicAdd(&sums[1], tv);
  }
}

// ---------------- Kernel C: final reduction -> 6 outputs ----------------
__global__ __launch_bounds__(256) void final_kernel(
    const float* __restrict__ sums, const int* __restrict__ rank,
    float* __restrict__ out) {
  __shared__ int s1[4], s5[4], s10[4], ssum[4];
  const int tid = threadIdx.x;
  int c1 = 0, c5 = 0, c10 = 0, cs = 0;
  for (int i = tid; i < NROWS; i += 256) {
    const int r = rank[i];
    c1  += (r < 1);
    c5  += (r < 5);
    c10 += (r < 10);
    cs  += r;
  }
  #pragma unroll
  for (int off = 32; off; off >>= 1) {
    c1  += __shfl_down(c1, off);
    c5  += __shfl_down(c5, off);
    c10 += __shfl_down(c10, off);
    cs  += __shfl_down(cs, off);
  }
  const int w = tid >> 6;
  if ((tid & 63) == 0) { s1[w] = c1; s5[w] = c5; s10[w] = c10; ssum[w] = cs; }
  __syncthreads();
  if (tid == 0) {
    int a1 = 0, a5 = 0, a10 = 0, as = 0;
    for (int k = 0; k < 4; ++k) { a1 += s1[k]; a5 += s5[k]; a10 += s10[k]; as += ssum[k]; }
    const float denom = 4096.0f * 4095.0f;
    out[0] = sums[0] / denom;
    out[1] = sums[1] / denom;
    out[2] = a1  / 4096.0f;
    out[3] = a5  / 4096.0f;
    out[4] = a10 / 4096.0f;
    out[5] = (float)as / 4096.0f;
  }
}

extern "C" void kernel_launch(void* const* d_in, const int* in_sizes, int n_in,
                              void* d_out, int out_size, void* d_ws, size_t ws_size,
                              hipStream_t stream) {
  const float* v = (const float*)d_in[0];
  const float* t = (const float*)d_in[1];
  float* out = (float*)d_out;

  float* diag = (float*)d_ws;
  int*   rank = (int*)((char*)d_ws + NROWS * sizeof(float));
  float* sums = (float*)((char*)d_ws + 2 * (size_t)NROWS * sizeof(float));

  hipLaunchKernelGGL(diag_kernel, dim3(NROWS / 4), dim3(256), 0, stream,
                     v, t, diag, rank, sums);
  hipLaunchKernelGGL(main_kernel, dim3(32, 16), dim3(256), 0, stream,
                     v, t, diag, sums, rank);
  hipLaunchKernelGGL(final_kernel, dim3(1), dim3(256), 0, stream, sums, rank, out);
}